// Round 10
// baseline (186.194 us; speedup 1.0000x reference)
//
#include <hip/hip_runtime.h>
#include <hip/hip_bf16.h>

// Problem constants
#define BATCH 2
#define SEQ   2048
#define EMB   1024
#define NH    16
#define HD    64
#define MROWS (BATCH*SEQ)   // 4096
#define NX    (MROWS*EMB)   // 4194304
#define NW    (EMB*EMB)     // 1048576 = 2^20

using f32x4  = __attribute__((ext_vector_type(4))) float;
using bf16x8 = __attribute__((ext_vector_type(8))) short;

#define GLOBAL_AS(p) ((const __attribute__((address_space(1))) void*)(p))
#define LDS_AS(p)    ((__attribute__((address_space(3))) void*)(p))

#define ROPE_L2 0.4152410118609203f    // log2(10000)/32
#define QSCALE  0.045084220027780106f  // (1/sqrt(E)) * log2(e)

// ---------------------------------------------------------------------------
// Fused f32->bf16 cast of x and the 4 weight matrices (Wq,Wk,Wv stacked),
// PLUS (tail blocks) the RoPE cos/sin table: ctab[s][ip].
// ---------------------------------------------------------------------------
__global__ void fused_cast_kernel(const float* __restrict__ x,
                                  const float* __restrict__ Wq,
                                  const float* __restrict__ Wk,
                                  const float* __restrict__ Wv,
                                  const float* __restrict__ Wo,
                                  __hip_bfloat16* __restrict__ xb,
                                  __hip_bfloat16* __restrict__ Wqkvb,
                                  __hip_bfloat16* __restrict__ Wob,
                                  float2* __restrict__ ctab) {
    if (blockIdx.x >= 4096) {
        // RoPE table tail: one entry per thread
        int e  = (blockIdx.x - 4096) * 256 + threadIdx.x;   // [0, 65536)
        int s  = e >> 5;
        int ip = e & 31;
        float inv = exp2f(-(float)ip * ROPE_L2);
        float fr  = (float)s * inv;
        float2 cs;
        cs.x = cosf(fr);
        cs.y = sinf(fr);
        ctab[e] = cs;
        return;
    }
    size_t i8 = (size_t)(blockIdx.x * 256 + threadIdx.x) * 8;
    const float* src;
    __hip_bfloat16* dst;
    if (i8 < (size_t)NX) {
        src = x + i8;
        dst = xb + i8;
    } else {
        size_t w = i8 - NX;
        int which = (int)(w >> 20);
        size_t local = w & (NW - 1);
        if (which < 3) {
            src = (which == 0 ? Wq : (which == 1 ? Wk : Wv)) + local;
            dst = Wqkvb + w;
        } else {
            src = Wo + local;
            dst = Wob + local;
        }
    }
    float4 a = *(const float4*)(src);
    float4 b = *(const float4*)(src + 4);
    union { uint4 u; ushort s[8]; } o;
    const float* f = (const float*)&a;
#pragma unroll
    for (int j = 0; j < 4; ++j) {
        __hip_bfloat16 h = __float2bfloat16(f[j]);
        o.s[j] = *(ushort*)&h;
    }
    f = (const float*)&b;
#pragma unroll
    for (int j = 0; j < 4; ++j) {
        __hip_bfloat16 h = __float2bfloat16(f[j]);
        o.s[4 + j] = *(ushort*)&h;
    }
    *(uint4*)dst = o.u;
}

// ---------------------------------------------------------------------------
// Fused QKV GEMM v2: C[M,3072] = A[M,K] * Wqkv[3072,K]^T, routed to Q/K/V.
// 256x256 tile, BK=64, 8 waves (2M x 4N, per-wave 128x64), double-buffered
// 128 KB dynamic LDS, grid (12,16) = 192 blocks = 1/CU (all co-resident).
// stage(next) issued BEFORE compute(cur) -> barrier drain ~free.
// T2 involution swizzle; RoPE fused in the epilogue; Q scaled by QSCALE.
// ---------------------------------------------------------------------------
__global__ __launch_bounds__(512, 2) void gemm_qkv_kernel(
        const __hip_bfloat16* __restrict__ A,
        const __hip_bfloat16* __restrict__ W,
        __hip_bfloat16* __restrict__ Qo,
        __hip_bfloat16* __restrict__ Ko,
        __hip_bfloat16* __restrict__ Vo,
        const float2* __restrict__ ctab, int M, int K) {
    extern __shared__ __hip_bfloat16 smem[];   // 131072 B
    // layout (elems): A0[16384] A1[16384] B0[16384] B1[16384]

    const int tid  = threadIdx.x;
    const int wave = tid >> 6;             // 0..7
    const int lane = tid & 63;
    const int quad = lane >> 4;
    const int l16  = lane & 15;
    const int m0   = blockIdx.y * 256;
    const int n0   = blockIdx.x * 256;
    const int mw   = wave >> 2;            // 0..1: A half (128 rows)
    const int nw   = wave & 3;             // 0..3: B quarter (64 rows)

    const int lr   = lane >> 3;            // row within 8-row chunk
    const int lg   = (lane & 7) ^ lr;      // pre-swizzled source col group
    const bool stA = (wave < 4);
    const int srow = (stA ? wave : wave - 4) * 64;
    const __hip_bfloat16* gbase =
        (stA ? A + (size_t)(m0 + srow) * K : W + (size_t)(n0 + srow) * K)
        + (size_t)lr * K + lg * 8;
    const int dbase = (stA ? 0 : 32768) + srow * 64;

    f32x4 acc[8][4] = {};

    const int nkt = K >> 6;                // 16 K-tiles

    // prologue: stage K-tile 0 into buf 0
#pragma unroll
    for (int t = 0; t < 8; ++t)
        __builtin_amdgcn_global_load_lds(
            GLOBAL_AS(gbase + (size_t)(t * 8) * K),
            LDS_AS(smem + dbase + t * 512), 16, 0, 0);
    __syncthreads();

    for (int it = 0; it < nkt; ++it) {
        const int cur = it & 1;
        if (it + 1 < nkt) {
            const __hip_bfloat16* gs = gbase + (size_t)(it + 1) * 64;
            __hip_bfloat16* dn = smem + dbase + (cur ? 0 : 16384);
#pragma unroll
            for (int t = 0; t < 8; ++t)
                __builtin_amdgcn_global_load_lds(
                    GLOBAL_AS(gs + (size_t)(t * 8) * K),
                    LDS_AS(dn + t * 512), 16, 0, 0);
        }

        const __hip_bfloat16* Ac = smem + (cur ? 16384 : 0);
        const __hip_bfloat16* Bc = smem + 32768 + (cur ? 16384 : 0);
#pragma unroll
        for (int ks = 0; ks < 2; ++ks) {
            bf16x8 bq[4];
#pragma unroll
            for (int j = 0; j < 4; ++j) {
                int br = nw * 64 + j * 16 + l16;
                bq[j] = *(const bf16x8*)(Bc + br * 64 + (((ks * 4 + quad) ^ (br & 7)) * 8));
            }
#pragma unroll
            for (int ih = 0; ih < 2; ++ih) {
                bf16x8 aq[4];
#pragma unroll
                for (int i2 = 0; i2 < 4; ++i2) {
                    int ar = mw * 128 + (ih * 4 + i2) * 16 + l16;
                    aq[i2] = *(const bf16x8*)(Ac + ar * 64 + (((ks * 4 + quad) ^ (ar & 7)) * 8));
                }
#pragma unroll
                for (int i2 = 0; i2 < 4; ++i2)
#pragma unroll
                    for (int j = 0; j < 4; ++j)
                        acc[ih * 4 + i2][j] = __builtin_amdgcn_mfma_f32_16x16x32_bf16(
                            aq[i2], bq[j], acc[ih * 4 + i2][j], 0, 0, 0);
            }
        }
        __syncthreads();   // drains this iter's stage (issued ~full iter ago)
    }

    const int tens = n0 >> 10;             // 256-tiles don't straddle 1024
    __hip_bfloat16* outp = (tens == 0) ? Qo : ((tens == 1) ? Ko : Vo);
    const int nbase = n0 & 1023;
    if (tens < 2) {
        // Q/K: apply RoPE on fp32 accumulators, then store (Q: * QSCALE)
        const float sgn  = (l16 & 1) ? 1.0f : -1.0f;
        const float qmul = (tens == 0) ? QSCALE : 1.0f;
#pragma unroll
        for (int i = 0; i < 8; ++i)
#pragma unroll
            for (int j = 0; j < 4; ++j) {
                int col  = nbase + nw * 64 + j * 16 + l16;
                int ip   = (col & 63) >> 1;           // pair index [0,32)
                int row0 = m0 + mw * 128 + i * 16 + quad * 4;
#pragma unroll
                for (int rr = 0; rr < 4; ++rr) {
                    float v = acc[i][j][rr];
                    float p = __shfl_xor(v, 1);
                    int sp  = (row0 + rr) & (SEQ - 1);
                    float2 cs = ctab[sp * 32 + ip];
                    float o = (v * cs.x + sgn * p * cs.y) * qmul;
                    outp[(size_t)(row0 + rr) * EMB + col] = __float2bfloat16(o);
                }
            }
    } else {
#pragma unroll
        for (int i = 0; i < 8; ++i)
#pragma unroll
            for (int j = 0; j < 4; ++j) {
                int col  = nbase + nw * 64 + j * 16 + l16;
                int row0 = m0 + mw * 128 + i * 16 + quad * 4;
#pragma unroll
                for (int rr = 0; rr < 4; ++rr)
                    outp[(size_t)(row0 + rr) * EMB + col] = __float2bfloat16(acc[i][j][rr]);
            }
    }
}

// ---------------------------------------------------------------------------
// O-projection GEMM: C[M,N] = A[M,K] * B[N,K]^T, fp32 out.
// 128x64 tile -> grid (16,32) = 512 blocks = 2/CU. T2 swizzle.
// ---------------------------------------------------------------------------
__global__ __launch_bounds__(256) void gemm_oproj_kernel(
        const __hip_bfloat16* __restrict__ A,
        const __hip_bfloat16* __restrict__ Bm,
        float* __restrict__ C, int M, int N, int K) {
    __shared__ __hip_bfloat16 As[128 * 64];
    __shared__ __hip_bfloat16 Bs[64 * 64];

    const int tid  = threadIdx.x;
    const int wave = tid >> 6;
    const int lane = tid & 63;
    const int quad = lane >> 4;
    const int l16  = lane & 15;
    const int m0   = blockIdx.y * 128;
    const int n0   = blockIdx.x * 64;
    const int wm   = (wave >> 1) * 64;
    const int wn   = (wave & 1) * 32;
    const int xr   = l16 & 7;

    f32x4 acc[4][2] = {};

    for (int k0 = 0; k0 < K; k0 += 64) {
#pragma unroll
        for (int it = 0; it < 4; ++it) {
            int flat = (wave * 4 + it) * 64 + lane;
            int row  = flat >> 3;
            int g    = (flat & 7) ^ (row & 7);
            const __hip_bfloat16* ga = A + (size_t)(m0 + row) * K + k0 + g * 8;
            __builtin_amdgcn_global_load_lds(GLOBAL_AS(ga),
                LDS_AS(As + (size_t)(wave * 4 + it) * 512), 16, 0, 0);
        }
#pragma unroll
        for (int it = 0; it < 2; ++it) {
            int flat = (wave * 2 + it) * 64 + lane;
            int row  = flat >> 3;
            int g    = (flat & 7) ^ (row & 7);
            const __hip_bfloat16* gb = Bm + (size_t)(n0 + row) * K + k0 + g * 8;
            __builtin_amdgcn_global_load_lds(GLOBAL_AS(gb),
                LDS_AS(Bs + (size_t)(wave * 2 + it) * 512), 16, 0, 0);
        }
        __syncthreads();

#pragma unroll
        for (int kk = 0; kk < 2; ++kk) {
            const int kg = (kk * 4 + quad) ^ xr;
            bf16x8 af[4], bfr[2];
#pragma unroll
            for (int i = 0; i < 4; ++i)
                af[i] = *(const bf16x8*)(&As[(wm + i * 16 + l16) * 64 + kg * 8]);
#pragma unroll
            for (int j = 0; j < 2; ++j)
                bfr[j] = *(const bf16x8*)(&Bs[(wn + j * 16 + l16) * 64 + kg * 8]);
#pragma unroll
            for (int i = 0; i < 4; ++i)
#pragma unroll
                for (int j = 0; j < 2; ++j)
                    acc[i][j] = __builtin_amdgcn_mfma_f32_16x16x32_bf16(
                        af[i], bfr[j], acc[i][j], 0, 0, 0);
        }
        __syncthreads();
    }

#pragma unroll
    for (int i = 0; i < 4; ++i)
#pragma unroll
        for (int j = 0; j < 2; ++j) {
            int col  = n0 + wn + j * 16 + l16;
            int row0 = m0 + wm + i * 16 + quad * 4;
#pragma unroll
            for (int rr = 0; rr < 4; ++rr)
                C[(size_t)(row0 + rr) * N + col] = acc[i][j][rr];
        }
}

// Single-instruction helpers (T12 recipe; no builtin for cvt_pk on gfx950)
__device__ inline uint cvt_pk_bf16(float lo, float hi) {
    uint r;
    asm("v_cvt_pk_bf16_f32 %0, %1, %2" : "=v"(r) : "v"(lo), "v"(hi));
    return r;
}
__device__ inline float exp2_raw(float x) {
    float r;
    asm("v_exp_f32 %0, %1" : "=v"(r) : "v"(x));
    return r;
}

// ---------------------------------------------------------------------------
// S^T flash attention (causal), fixed-base exp2 softmax (QSCALE*log2e in Q).
//
// v7 (resubmitted unchanged after R9 infra failure):
//  * Balanced-pair dispatch: all 512 blocks co-resident (2/CU); di & di+256
//    co-locate -> pair heavy with light so work(di)+work(di+256) = 36 iters
//    on every CU (old LPT: 48..20).
//  * VTs pair-column XOR swizzle P(d,p) = p ^ (4*(d&1) + 8*((d>>1)&1)):
//    PV ds_read_b32 4-way -> ~2-way (free); pack-writes stay 2-way.
//    Same involution write & read (rule #21).
// v6 kept: 128-row q-tiles, 8 waves, single owner; register-resident P;
//    swizzled K gll; ones-MFMA row-sum; cvt_pk; raw v_exp_f32; setprio.
// ---------------------------------------------------------------------------
__global__ __launch_bounds__(512) void attn_mfma_kernel(
        const __hip_bfloat16* __restrict__ Qb,
        const __hip_bfloat16* __restrict__ Kb,
        const __hip_bfloat16* __restrict__ Vb,
        __hip_bfloat16* __restrict__ Attnb) {
    const int di   = blockIdx.y * 16 + blockIdx.x;   // dispatch index
    // balanced pairs: work(di) + work(di+256) == 36 iters
    const int qt   = (di < 256) ? (15 - (di >> 5)) : ((di - 256) >> 5);
    const int bh   = di & 31;
    const int b    = bh >> 4;
    const int h    = bh & (NH - 1);
    const int tid  = threadIdx.x;
    const int wave = tid >> 6;
    const int lane = tid & 63;
    const int quad = lane >> 4;
    const int l16  = lane & 15;

    __shared__ __hip_bfloat16 Ks[2][64 * 64];  // 16 KB, XOR col-swizzled, key-major
    __shared__ uint VTs[2][64][33];            // 16.5 KB, packed V^T pairs (XOR cols)

    const int pc   = tid >> 4;                 // 0..31: key pair (V staging)
    const int sgg  = tid & 15;                 // dim group of 4 (V staging)
    const int d0   = sgg * 4;
    const int lr   = lane >> 3;                // gll: row within 8-row chunk
    const int lg   = (lane & 7) ^ lr;          // pre-swizzled source col group
    const size_t ksrc_lane = (size_t)lr * EMB + lg * 8;
    // PV read-side pair-col swizzle term: SW(d) = 4*(d&1) + 8*((d>>1)&1),
    // d = nb*16 + l16 -> depends only on l16&3
    const int swd = ((l16 & 1) << 2) | (((l16 >> 1) & 1) << 3);

    const __hip_bfloat16* Kbase = Kb + (size_t)b * SEQ * EMB + h * HD;
    const __hip_bfloat16* Vbase = Vb + (size_t)b * SEQ * EMB + h * HD;

    // B-operand of all-ones bf16 (1.0 = 0x3F80) for the row-sum MFMA
    union { uint u[4]; bf16x8 v; } onesu;
    onesu.u[0] = 0x3F803F80u; onesu.u[1] = 0x3F803F80u;
    onesu.u[2] = 0x3F803F80u; onesu.u[3] = 0x3F803F80u;
    const bf16x8 ones = onesu.v;

    const int  nt      = 2 * qt + 2;           // k-tiles 0 .. 2qt+1
    const bool lowHalf = (wave < 4);
    const int  we      = lowHalf ? wave : wave - 4;  // 16-row block within 64

    // Q fragments (B operand; layout identical to A): lane = q-row l16
    const int qrow0 = qt * 128 + wave * 16;
    bf16x8 qf[2];
    {
        const __hip_bfloat16* qp =
            Qb + (size_t)(b * SEQ + qrow0 + l16) * EMB + h * HD + quad * 8;
        qf[0] = *(const bf16x8*)(qp);
        qf[1] = *(const bf16x8*)(qp + 32);
    }

    f32x4 of[4]  = {};       // O: col d = nb*16+l16, row q = quad*4+r
    f32x4 of_sum = {};       // L: row q = quad*4+r (all l16 identical)

    // prologue: stage tile 0 (V -> regs, K -> LDS buf0 via gll)
    const __hip_bfloat16* kgp = Kbase;
    const __hip_bfloat16* vgp = Vbase + (size_t)(2 * pc) * EMB + d0;
    uint2 va = *(const uint2*)(vgp);
    uint2 vb = *(const uint2*)(vgp + EMB);
    __builtin_amdgcn_global_load_lds(
        GLOBAL_AS(kgp + (size_t)(8 * wave) * EMB + ksrc_lane),
        LDS_AS(&Ks[0][wave * 512]), 16, 0, 0);

    for (int i = 0; i < nt; ++i) {
        const int cur = i & 1;

        // V^T pack -> LDS with pair-col XOR swizzle (writes stay 2-way free):
        // row d0+2j   (d&3 = 2j)   -> col pc ^ (8j)
        // row d0+2j+1 (d&3 = 2j+1) -> col pc ^ (8j) ^ 4
        {
            const uint* vau = (const uint*)&va;
            const uint* vbu = (const uint*)&vb;
#pragma unroll
            for (int j = 0; j < 2; ++j) {
                VTs[cur][d0 + 2 * j][pc ^ (8 * j)] =
                    __builtin_amdgcn_perm(vbu[j], vau[j], 0x05040100u);
                VTs[cur][d0 + 2 * j + 1][(pc ^ (8 * j)) ^ 4] =
                    __builtin_amdgcn_perm(vbu[j], vau[j], 0x07060302u);
            }
        }
        __syncthreads();     // drains gll(i): Ks[cur] + VTs[cur] ready

        if (i + 1 < nt) {    // stage tile i+1; drains at next barrier
            kgp += (size_t)64 * EMB;
            vgp += (size_t)64 * EMB;
            va = *(const uint2*)(vgp);
            vb = *(const uint2*)(vgp + EMB);
            __builtin_amdgcn_global_load_lds(
                GLOBAL_AS(kgp + (size_t)(8 * wave) * EMB + ksrc_lane),
                LDS_AS(&Ks[cur ^ 1][wave * 512]), 16, 0, 0);
        }

        const bool diagA = (i == 2 * qt);       // low waves diag, high full
        const bool diagB = (i == 2 * qt + 1);   // low waves skip, high diag
        const bool skip  = diagB && lowHalf;
        if (skip) continue;                     // wave-uniform; barrier already passed
        const bool masking = (diagA && lowHalf) || (diagB && !lowHalf);

        // ---- S^T = K·Q^T: sc[mb] covers keys mb*16.. for q-rows of wave ----
        const __hip_bfloat16* KsC = Ks[cur];
        f32x4 sc[4];
        __builtin_amdgcn_s_setprio(1);
#pragma unroll
        for (int mb = 0; mb < 4; ++mb) {
            f32x4 a = {};
            if (!(masking && mb > we)) {
                int krow = mb * 16 + l16;
#pragma unroll
                for (int kb = 0; kb < 2; ++kb) {
                    int kg = (kb * 4 + quad) ^ (krow & 7);
                    bf16x8 kf = *(const bf16x8*)(&KsC[krow * 64 + kg * 8]);
                    a = __builtin_amdgcn_mfma_f32_16x16x32_bf16(kf, qf[kb], a, 0, 0, 0);
                }
            }
            sc[mb] = a;
        }
        __builtin_amdgcn_s_setprio(0);

        // mask: key = mb*16+quad*4+r  vs  q = we*16+l16 (same 64-row base)
        if (masking) {
#pragma unroll
            for (int mb = 0; mb < 4; ++mb)
#pragma unroll
                for (int r = 0; r < 4; ++r)
                    if (mb * 16 + quad * 4 + r > we * 16 + l16)
                        sc[mb][r] = -16384.0f;
        }

        // ---- p = 2^s via raw v_exp_f32 (row-sum via ones-MFMA below) ----
#pragma unroll
        for (int mb = 0; mb < 4; ++mb)
#pragma unroll
            for (int r = 0; r < 4; ++r)
                sc[mb][r] = exp2_raw(sc[mb][r]);

        // ---- P stays in registers (k-permuted; matches V pair reads) ----
        bf16x8 pf[2];
        {
            union { uint u[4]; bf16x8 v; } t;
            t.u[0] = cvt_pk_bf16(sc[0][0], sc[0][1]);
            t.u[1] = cvt_pk_bf16(sc[0][2], sc[0][3]);
            t.u[2] = cvt_pk_bf16(sc[1][0], sc[1][1]);
            t.u[3] = cvt_pk_bf16(sc[1][2], sc[1][3]);
            pf[0] = t.v;
            t.u[0] = cvt_pk_bf16(sc[2][0], sc[2][1]);
            t.u[1] = cvt_pk_bf16(sc[2][2], sc[2][3]);
            t.u[2] = cvt_pk_bf16(sc[3][0], sc[3][1]);
            t.u[3] = cvt_pk_bf16(sc[3][2], sc[3][3]);
            pf[1] = t.v;
        }

        // ---- O += P V ; L += P 1 (row-sum on the matrix pipe) ----
        const uint* VT0 = &VTs[cur][0][0];
        __builtin_amdgcn_s_setprio(1);
#pragma unroll
        for (int nb = 0; nb < 4; ++nb) {
            const uint* vrow = VT0 + (size_t)(nb * 16 + l16) * 33;
#pragma unroll
            for (int c = 0; c < 2; ++c) {
                const int p0 = (c * 16 + 2 * quad) ^ swd;       // swd bit0 == 0
                const int p2 = (c * 16 + 8 + 2 * quad) ^ swd;
                union { uint u[4]; bf16x8 v; } vf;
                vf.u[0] = vrow[p0];
                vf.u[1] = vrow[p0 + 1];
                vf.u[2] = vrow[p2];
                vf.u[3] = vrow[p2 + 1];
                of[nb] = __builtin_amdgcn_mfma_f32_16x16x32_bf16(
                    pf[c], vf.v, of[nb], 0, 0, 0);
            }
        }
        of_sum = __builtin_amdgcn_mfma_f32_16x16x32_bf16(pf[0], ones, of_sum, 0, 0, 0);
        of_sum = __builtin_amdgcn_mfma_f32_16x16x32_bf16(pf[1], ones, of_sum, 0, 0, 0);
        __builtin_amdgcn_s_setprio(0);
    }

    // ---- epilogue: of_sum[r] = L[q = quad*4 + r]; final write always ----
    const int rl0 = quad * 4;
    float linv[4];
#pragma unroll
    for (int r = 0; r < 4; ++r)
        linv[r] = 1.0f / of_sum[r];
#pragma unroll
    for (int nb = 0; nb < 4; ++nb)
#pragma unroll
        for (int r = 0; r < 4; ++r) {
            float v = of[nb][r] * linv[r];
            Attnb[(size_t)(b * SEQ + qrow0 + rl0 + r) * EMB + h * HD + nb * 16 + l16] =
                __float2bfloat16(v);
        }
}

// ---------------------------------------------------------------------------
extern "C" void kernel_launch(void* const* d_in, const int* in_sizes, int n_in,
                              void* d_out, int out_size, void* d_ws, size_t ws_size,
                              hipStream_t stream) {
    const float* x  = (const float*)d_in[0];
    const float* Wq = (const float*)d_in[1];
    const float* Wk = (const float*)d_in[2];
    const float* Wv = (const float*)d_in[3];
    const float* Wo = (const float*)d_in[4];
    float* out = (float*)d_out;

    char* ws = (char*)d_ws;
    size_t off = 0;
    auto alloc = [&](size_t bytes) -> void* {
        void* p = ws + off;
        off += (bytes + 255) & ~(size_t)255;
        return p;
    };

    __hip_bfloat16* xb    = (__hip_bfloat16*)alloc((size_t)NX * 2);
    __hip_bfloat16* Wqkvb = (__hip_bfloat16*)alloc((size_t)NW * 3 * 2);
    __hip_bfloat16* Wob   = (__hip_bfloat16*)alloc((size_t)NW * 2);
    __hip_bfloat16* Qbuf  = (__hip_bfloat16*)alloc((size_t)NX * 2);
    __hip_bfloat16* Kbuf  = (__hip_bfloat16*)alloc((size_t)NX * 2);
    __hip_bfloat16* Vbuf  = (__hip_bfloat16*)alloc((size_t)NX * 2);
    __hip_bfloat16* Attnb = (__hip_bfloat16*)alloc((size_t)NX * 2);
    float2*         ctab  = (float2*)alloc((size_t)SEQ * 32 * sizeof(float2));

    // one-time: allow 128 KB dynamic LDS for the big-tile qkv GEMM
    static bool attrDone = false;
    if (!attrDone) {
        (void)hipFuncSetAttribute((const void*)gemm_qkv_kernel,
                                  hipFuncAttributeMaxDynamicSharedMemorySize,
                                  131072);
        attrDone = true;
    }

    // fused casts + RoPE table (256 tail blocks)
    fused_cast_kernel<<<(NX + 4 * NW) / (256 * 8) + 256, 256, 0, stream>>>(
        x, Wq, Wk, Wv, Wo, xb, Wqkvb, Wob, ctab);

    // fused QKV projection + RoPE epilogue (256x256 big-tile, 1 block/CU)
    dim3 qgrid(3072 / 256, MROWS / 256);    // (12, 16) = 192 blocks
    gemm_qkv_kernel<<<qgrid, 512, 131072, stream>>>(xb, Wqkvb, Qbuf, Kbuf, Vbuf,
                                                    ctab, MROWS, EMB);

    // S^T flash attention: 128-row q-tiles, single owner, balanced pairs
    dim3 agrid(16, 32);
    attn_mfma_kernel<<<agrid, 512, 0, stream>>>(Qbuf, Kbuf, Vbuf, Attnb);

    // output projection -> fp32 d_out (128x64 tiles, 512 blocks)
    dim3 ggrid(EMB / 64, MROWS / 128);
    gemm_oproj_kernel<<<ggrid, 256, 0, stream>>>(Attnb, Wob, out, MROWS, EMB, EMB);
}

// Round 13
// 185.583 us; speedup vs baseline: 1.0033x; 1.0033x over previous
//
#include <hip/hip_runtime.h>
#include <hip/hip_bf16.h>

// Problem constants
#define BATCH 2
#define SEQ   2048
#define EMB   1024
#define NH    16
#define HD    64
#define MROWS (BATCH*SEQ)   // 4096
#define NX    (MROWS*EMB)   // 4194304
#define NW    (EMB*EMB)     // 1048576 = 2^20

using f32x4  = __attribute__((ext_vector_type(4))) float;
using bf16x8 = __attribute__((ext_vector_type(8))) short;

#define GLOBAL_AS(p) ((const __attribute__((address_space(1))) void*)(p))
#define LDS_AS(p)    ((__attribute__((address_space(3))) void*)(p))

#define ROPE_L2 0.4152410118609203f    // log2(10000)/32
#define QSCALE  0.045084220027780106f  // (1/sqrt(E)) * log2(e)

// ---------------------------------------------------------------------------
// Fused f32->bf16 cast of x and the 4 weight matrices (Wq,Wk,Wv stacked),
// PLUS (tail blocks) the RoPE cos/sin table: ctab[s][ip].
// ---------------------------------------------------------------------------
__global__ void fused_cast_kernel(const float* __restrict__ x,
                                  const float* __restrict__ Wq,
                                  const float* __restrict__ Wk,
                                  const float* __restrict__ Wv,
                                  const float* __restrict__ Wo,
                                  __hip_bfloat16* __restrict__ xb,
                                  __hip_bfloat16* __restrict__ Wqkvb,
                                  __hip_bfloat16* __restrict__ Wob,
                                  float2* __restrict__ ctab) {
    if (blockIdx.x >= 4096) {
        // RoPE table tail: one entry per thread
        int e  = (blockIdx.x - 4096) * 256 + threadIdx.x;   // [0, 65536)
        int s  = e >> 5;
        int ip = e & 31;
        float inv = exp2f(-(float)ip * ROPE_L2);
        float fr  = (float)s * inv;
        float2 cs;
        cs.x = cosf(fr);
        cs.y = sinf(fr);
        ctab[e] = cs;
        return;
    }
    size_t i8 = (size_t)(blockIdx.x * 256 + threadIdx.x) * 8;
    const float* src;
    __hip_bfloat16* dst;
    if (i8 < (size_t)NX) {
        src = x + i8;
        dst = xb + i8;
    } else {
        size_t w = i8 - NX;
        int which = (int)(w >> 20);
        size_t local = w & (NW - 1);
        if (which < 3) {
            src = (which == 0 ? Wq : (which == 1 ? Wk : Wv)) + local;
            dst = Wqkvb + w;
        } else {
            src = Wo + local;
            dst = Wob + local;
        }
    }
    float4 a = *(const float4*)(src);
    float4 b = *(const float4*)(src + 4);
    union { uint4 u; ushort s[8]; } o;
    const float* f = (const float*)&a;
#pragma unroll
    for (int j = 0; j < 4; ++j) {
        __hip_bfloat16 h = __float2bfloat16(f[j]);
        o.s[j] = *(ushort*)&h;
    }
    f = (const float*)&b;
#pragma unroll
    for (int j = 0; j < 4; ++j) {
        __hip_bfloat16 h = __float2bfloat16(f[j]);
        o.s[4 + j] = *(ushort*)&h;
    }
    *(uint4*)dst = o.u;
}

// ---------------------------------------------------------------------------
// Fused QKV GEMM v2: C[M,3072] = A[M,K] * Wqkv[3072,K]^T, routed to Q/K/V.
// 256x256 tile, BK=64, 8 waves (2M x 4N, per-wave 128x64), double-buffered
// 128 KB dynamic LDS, grid (12,16) = 192 blocks = 1/CU (all co-resident).
// stage(next) issued BEFORE compute(cur) -> barrier drain ~free.
// T2 involution swizzle; RoPE fused in the epilogue; Q scaled by QSCALE.
// ---------------------------------------------------------------------------
__global__ __launch_bounds__(512, 2) void gemm_qkv_kernel(
        const __hip_bfloat16* __restrict__ A,
        const __hip_bfloat16* __restrict__ W,
        __hip_bfloat16* __restrict__ Qo,
        __hip_bfloat16* __restrict__ Ko,
        __hip_bfloat16* __restrict__ Vo,
        const float2* __restrict__ ctab, int M, int K) {
    extern __shared__ __hip_bfloat16 smem[];   // 131072 B
    // layout (elems): A0[16384] A1[16384] B0[16384] B1[16384]

    const int tid  = threadIdx.x;
    const int wave = tid >> 6;             // 0..7
    const int lane = tid & 63;
    const int quad = lane >> 4;
    const int l16  = lane & 15;
    const int m0   = blockIdx.y * 256;
    const int n0   = blockIdx.x * 256;
    const int mw   = wave >> 2;            // 0..1: A half (128 rows)
    const int nw   = wave & 3;             // 0..3: B quarter (64 rows)

    const int lr   = lane >> 3;            // row within 8-row chunk
    const int lg   = (lane & 7) ^ lr;      // pre-swizzled source col group
    const bool stA = (wave < 4);
    const int srow = (stA ? wave : wave - 4) * 64;
    const __hip_bfloat16* gbase =
        (stA ? A + (size_t)(m0 + srow) * K : W + (size_t)(n0 + srow) * K)
        + (size_t)lr * K + lg * 8;
    const int dbase = (stA ? 0 : 32768) + srow * 64;

    f32x4 acc[8][4] = {};

    const int nkt = K >> 6;                // 16 K-tiles

    // prologue: stage K-tile 0 into buf 0
#pragma unroll
    for (int t = 0; t < 8; ++t)
        __builtin_amdgcn_global_load_lds(
            GLOBAL_AS(gbase + (size_t)(t * 8) * K),
            LDS_AS(smem + dbase + t * 512), 16, 0, 0);
    __syncthreads();

    for (int it = 0; it < nkt; ++it) {
        const int cur = it & 1;
        if (it + 1 < nkt) {
            const __hip_bfloat16* gs = gbase + (size_t)(it + 1) * 64;
            __hip_bfloat16* dn = smem + dbase + (cur ? 0 : 16384);
#pragma unroll
            for (int t = 0; t < 8; ++t)
                __builtin_amdgcn_global_load_lds(
                    GLOBAL_AS(gs + (size_t)(t * 8) * K),
                    LDS_AS(dn + t * 512), 16, 0, 0);
        }

        const __hip_bfloat16* Ac = smem + (cur ? 16384 : 0);
        const __hip_bfloat16* Bc = smem + 32768 + (cur ? 16384 : 0);
#pragma unroll
        for (int ks = 0; ks < 2; ++ks) {
            bf16x8 bq[4];
#pragma unroll
            for (int j = 0; j < 4; ++j) {
                int br = nw * 64 + j * 16 + l16;
                bq[j] = *(const bf16x8*)(Bc + br * 64 + (((ks * 4 + quad) ^ (br & 7)) * 8));
            }
#pragma unroll
            for (int ih = 0; ih < 2; ++ih) {
                bf16x8 aq[4];
#pragma unroll
                for (int i2 = 0; i2 < 4; ++i2) {
                    int ar = mw * 128 + (ih * 4 + i2) * 16 + l16;
                    aq[i2] = *(const bf16x8*)(Ac + ar * 64 + (((ks * 4 + quad) ^ (ar & 7)) * 8));
                }
#pragma unroll
                for (int i2 = 0; i2 < 4; ++i2)
#pragma unroll
                    for (int j = 0; j < 4; ++j)
                        acc[ih * 4 + i2][j] = __builtin_amdgcn_mfma_f32_16x16x32_bf16(
                            aq[i2], bq[j], acc[ih * 4 + i2][j], 0, 0, 0);
            }
        }
        __syncthreads();   // drains this iter's stage (issued ~full iter ago)
    }

    const int tens = n0 >> 10;             // 256-tiles don't straddle 1024
    __hip_bfloat16* outp = (tens == 0) ? Qo : ((tens == 1) ? Ko : Vo);
    const int nbase = n0 & 1023;
    if (tens < 2) {
        // Q/K: apply RoPE on fp32 accumulators, then store (Q: * QSCALE)
        const float sgn  = (l16 & 1) ? 1.0f : -1.0f;
        const float qmul = (tens == 0) ? QSCALE : 1.0f;
#pragma unroll
        for (int i = 0; i < 8; ++i)
#pragma unroll
            for (int j = 0; j < 4; ++j) {
                int col  = nbase + nw * 64 + j * 16 + l16;
                int ip   = (col & 63) >> 1;           // pair index [0,32)
                int row0 = m0 + mw * 128 + i * 16 + quad * 4;
#pragma unroll
                for (int rr = 0; rr < 4; ++rr) {
                    float v = acc[i][j][rr];
                    float p = __shfl_xor(v, 1);
                    int sp  = (row0 + rr) & (SEQ - 1);
                    float2 cs = ctab[sp * 32 + ip];
                    float o = (v * cs.x + sgn * p * cs.y) * qmul;
                    outp[(size_t)(row0 + rr) * EMB + col] = __float2bfloat16(o);
                }
            }
    } else {
#pragma unroll
        for (int i = 0; i < 8; ++i)
#pragma unroll
            for (int j = 0; j < 4; ++j) {
                int col  = nbase + nw * 64 + j * 16 + l16;
                int row0 = m0 + mw * 128 + i * 16 + quad * 4;
#pragma unroll
                for (int rr = 0; rr < 4; ++rr)
                    outp[(size_t)(row0 + rr) * EMB + col] = __float2bfloat16(acc[i][j][rr]);
            }
    }
}

// ---------------------------------------------------------------------------
// O-projection GEMM: C[M,N] = A[M,K] * B[N,K]^T, fp32 out.
// 128x64 tile -> grid (16,32) = 512 blocks = 2/CU. T2 swizzle.
// ---------------------------------------------------------------------------
__global__ __launch_bounds__(256) void gemm_oproj_kernel(
        const __hip_bfloat16* __restrict__ A,
        const __hip_bfloat16* __restrict__ Bm,
        float* __restrict__ C, int M, int N, int K) {
    __shared__ __hip_bfloat16 As[128 * 64];
    __shared__ __hip_bfloat16 Bs[64 * 64];

    const int tid  = threadIdx.x;
    const int wave = tid >> 6;
    const int lane = tid & 63;
    const int quad = lane >> 4;
    const int l16  = lane & 15;
    const int m0   = blockIdx.y * 128;
    const int n0   = blockIdx.x * 64;
    const int wm   = (wave >> 1) * 64;
    const int wn   = (wave & 1) * 32;
    const int xr   = l16 & 7;

    f32x4 acc[4][2] = {};

    for (int k0 = 0; k0 < K; k0 += 64) {
#pragma unroll
        for (int it = 0; it < 4; ++it) {
            int flat = (wave * 4 + it) * 64 + lane;
            int row  = flat >> 3;
            int g    = (flat & 7) ^ (row & 7);
            const __hip_bfloat16* ga = A + (size_t)(m0 + row) * K + k0 + g * 8;
            __builtin_amdgcn_global_load_lds(GLOBAL_AS(ga),
                LDS_AS(As + (size_t)(wave * 4 + it) * 512), 16, 0, 0);
        }
#pragma unroll
        for (int it = 0; it < 2; ++it) {
            int flat = (wave * 2 + it) * 64 + lane;
            int row  = flat >> 3;
            int g    = (flat & 7) ^ (row & 7);
            const __hip_bfloat16* gb = Bm + (size_t)(n0 + row) * K + k0 + g * 8;
            __builtin_amdgcn_global_load_lds(GLOBAL_AS(gb),
                LDS_AS(Bs + (size_t)(wave * 2 + it) * 512), 16, 0, 0);
        }
        __syncthreads();

#pragma unroll
        for (int kk = 0; kk < 2; ++kk) {
            const int kg = (kk * 4 + quad) ^ xr;
            bf16x8 af[4], bfr[2];
#pragma unroll
            for (int i = 0; i < 4; ++i)
                af[i] = *(const bf16x8*)(&As[(wm + i * 16 + l16) * 64 + kg * 8]);
#pragma unroll
            for (int j = 0; j < 2; ++j)
                bfr[j] = *(const bf16x8*)(&Bs[(wn + j * 16 + l16) * 64 + kg * 8]);
#pragma unroll
            for (int i = 0; i < 4; ++i)
#pragma unroll
                for (int j = 0; j < 2; ++j)
                    acc[i][j] = __builtin_amdgcn_mfma_f32_16x16x32_bf16(
                        af[i], bfr[j], acc[i][j], 0, 0, 0);
        }
        __syncthreads();
    }

#pragma unroll
    for (int i = 0; i < 4; ++i)
#pragma unroll
        for (int j = 0; j < 2; ++j) {
            int col  = n0 + wn + j * 16 + l16;
            int row0 = m0 + wm + i * 16 + quad * 4;
#pragma unroll
            for (int rr = 0; rr < 4; ++rr)
                C[(size_t)(row0 + rr) * N + col] = acc[i][j][rr];
        }
}

// Single-instruction helpers (T12 recipe; no builtin for cvt_pk on gfx950)
__device__ inline uint cvt_pk_bf16(float lo, float hi) {
    uint r;
    asm("v_cvt_pk_bf16_f32 %0, %1, %2" : "=v"(r) : "v"(lo), "v"(hi));
    return r;
}
__device__ inline float exp2_raw(float x) {
    float r;
    asm("v_exp_f32 %0, %1" : "=v"(r) : "v"(x));
    return r;
}

// ---------------------------------------------------------------------------
// S^T flash attention (causal), fixed-base exp2 softmax (QSCALE*log2e in Q).
//
// v7 (verified @ R10, 186.2us total): single k-tile per barrier.
//  * Balanced-pair dispatch (null vs LPT but harmless; kept as measured).
//  * VTs pair-column XOR swizzle (null but harmless; kept as measured).
// v6 core: 128-row q-tiles, 8 waves, single owner; register-resident P
//  (MFMA k-slot permutation invariance); K direct global->LDS with
//  pre-swizzled source; ones-MFMA row-sum; cvt_pk P-pack; raw v_exp_f32;
//  T5 setprio; 1 barrier/tile dbuf with post-barrier prefetch issue.
// NOTE: paired-tile ILP (R11/R12) produced wrong results on HW twice despite
// passing repeated static audit — reverted to this verified structure.
// ---------------------------------------------------------------------------
__global__ __launch_bounds__(512) void attn_mfma_kernel(
        const __hip_bfloat16* __restrict__ Qb,
        const __hip_bfloat16* __restrict__ Kb,
        const __hip_bfloat16* __restrict__ Vb,
        __hip_bfloat16* __restrict__ Attnb) {
    const int di   = blockIdx.y * 16 + blockIdx.x;   // dispatch index
    // balanced pairs: work(di) + work(di+256) == 36 iters
    const int qt   = (di < 256) ? (15 - (di >> 5)) : ((di - 256) >> 5);
    const int bh   = di & 31;
    const int b    = bh >> 4;
    const int h    = bh & (NH - 1);
    const int tid  = threadIdx.x;
    const int wave = tid >> 6;
    const int lane = tid & 63;
    const int quad = lane >> 4;
    const int l16  = lane & 15;

    __shared__ __hip_bfloat16 Ks[2][64 * 64];  // 16 KB, XOR col-swizzled, key-major
    __shared__ uint VTs[2][64][33];            // 16.5 KB, packed V^T pairs (XOR cols)

    const int pc   = tid >> 4;                 // 0..31: key pair (V staging)
    const int sgg  = tid & 15;                 // dim group of 4 (V staging)
    const int d0   = sgg * 4;
    const int lr   = lane >> 3;                // gll: row within 8-row chunk
    const int lg   = (lane & 7) ^ lr;          // pre-swizzled source col group
    const size_t ksrc_lane = (size_t)lr * EMB + lg * 8;
    // PV read-side pair-col swizzle term: SW(d) = 4*(d&1) + 8*((d>>1)&1)
    const int swd = ((l16 & 1) << 2) | (((l16 >> 1) & 1) << 3);

    const __hip_bfloat16* Kbase = Kb + (size_t)b * SEQ * EMB + h * HD;
    const __hip_bfloat16* Vbase = Vb + (size_t)b * SEQ * EMB + h * HD;

    // B-operand of all-ones bf16 (1.0 = 0x3F80) for the row-sum MFMA
    union { uint u[4]; bf16x8 v; } onesu;
    onesu.u[0] = 0x3F803F80u; onesu.u[1] = 0x3F803F80u;
    onesu.u[2] = 0x3F803F80u; onesu.u[3] = 0x3F803F80u;
    const bf16x8 ones = onesu.v;

    const int  nt      = 2 * qt + 2;           // k-tiles 0 .. 2qt+1
    const bool lowHalf = (wave < 4);
    const int  we      = lowHalf ? wave : wave - 4;  // 16-row block within 64

    // Q fragments (B operand; layout identical to A): lane = q-row l16
    const int qrow0 = qt * 128 + wave * 16;
    bf16x8 qf0, qf1;
    {
        const __hip_bfloat16* qp =
            Qb + (size_t)(b * SEQ + qrow0 + l16) * EMB + h * HD + quad * 8;
        qf0 = *(const bf16x8*)(qp);
        qf1 = *(const bf16x8*)(qp + 32);
    }

    f32x4 of[4]  = {};       // O: col d = nb*16+l16, row q = quad*4+r
    f32x4 of_sum = {};       // L: row q = quad*4+r (all l16 identical)

    // prologue: stage tile 0 (V -> regs, K -> LDS buf0 via gll)
    const __hip_bfloat16* kgp = Kbase;
    const __hip_bfloat16* vgp = Vbase + (size_t)(2 * pc) * EMB + d0;
    uint2 va = *(const uint2*)(vgp);
    uint2 vb = *(const uint2*)(vgp + EMB);
    __builtin_amdgcn_global_load_lds(
        GLOBAL_AS(kgp + (size_t)(8 * wave) * EMB + ksrc_lane),
        LDS_AS(&Ks[0][wave * 512]), 16, 0, 0);

    for (int i = 0; i < nt; ++i) {
        const int cur = i & 1;

        // V^T pack -> LDS with pair-col XOR swizzle:
        // row d0+2j   -> col pc ^ (8j); row d0+2j+1 -> col (pc ^ (8j)) ^ 4
        {
            const uint* vau = (const uint*)&va;
            const uint* vbu = (const uint*)&vb;
#pragma unroll
            for (int j = 0; j < 2; ++j) {
                VTs[cur][d0 + 2 * j][pc ^ (8 * j)] =
                    __builtin_amdgcn_perm(vbu[j], vau[j], 0x05040100u);
                VTs[cur][d0 + 2 * j + 1][(pc ^ (8 * j)) ^ 4] =
                    __builtin_amdgcn_perm(vbu[j], vau[j], 0x07060302u);
            }
        }
        __syncthreads();     // drains gll(i): Ks[cur] + VTs[cur] ready

        if (i + 1 < nt) {    // stage tile i+1; drains at next barrier
            kgp += (size_t)64 * EMB;
            vgp += (size_t)64 * EMB;
            va = *(const uint2*)(vgp);
            vb = *(const uint2*)(vgp + EMB);
            __builtin_amdgcn_global_load_lds(
                GLOBAL_AS(kgp + (size_t)(8 * wave) * EMB + ksrc_lane),
                LDS_AS(&Ks[cur ^ 1][wave * 512]), 16, 0, 0);
        }

        const bool diagA = (i == 2 * qt);       // low waves diag, high full
        const bool diagB = (i == 2 * qt + 1);   // low waves skip, high diag
        const bool skip  = diagB && lowHalf;
        if (skip) continue;                     // wave-uniform; barrier already passed
        const bool masking = (diagA && lowHalf) || (diagB && !lowHalf);

        // ---- S^T = K·Q^T: sc[mb] covers keys mb*16.. for q-rows of wave ----
        const __hip_bfloat16* KsC = Ks[cur];
        f32x4 sc[4];
        __builtin_amdgcn_s_setprio(1);
#pragma unroll
        for (int mb = 0; mb < 4; ++mb) {
            f32x4 a = {};
            if (!(masking && mb > we)) {
                int krow = mb * 16 + l16;
#pragma unroll
                for (int kb = 0; kb < 2; ++kb) {
                    int kg = (kb * 4 + quad) ^ (krow & 7);
                    bf16x8 kf = *(const bf16x8*)(&KsC[krow * 64 + kg * 8]);
                    a = __builtin_amdgcn_mfma_f32_16x16x32_bf16(
                        kf, kb ? qf1 : qf0, a, 0, 0, 0);
                }
            }
            sc[mb] = a;
        }
        __builtin_amdgcn_s_setprio(0);

        // mask: key = mb*16+quad*4+r  vs  q = we*16+l16 (same 64-row base)
        if (masking) {
#pragma unroll
            for (int mb = 0; mb < 4; ++mb)
#pragma unroll
                for (int r = 0; r < 4; ++r)
                    if (mb * 16 + quad * 4 + r > we * 16 + l16)
                        sc[mb][r] = -16384.0f;
        }

        // ---- p = 2^s via raw v_exp_f32 (row-sum via ones-MFMA below) ----
#pragma unroll
        for (int mb = 0; mb < 4; ++mb)
#pragma unroll
            for (int r = 0; r < 4; ++r)
                sc[mb][r] = exp2_raw(sc[mb][r]);

        // ---- P stays in registers (k-permuted; matches V pair reads) ----
        bf16x8 pf0, pf1;
        {
            union { uint u[4]; bf16x8 v; } t;
            t.u[0] = cvt_pk_bf16(sc[0][0], sc[0][1]);
            t.u[1] = cvt_pk_bf16(sc[0][2], sc[0][3]);
            t.u[2] = cvt_pk_bf16(sc[1][0], sc[1][1]);
            t.u[3] = cvt_pk_bf16(sc[1][2], sc[1][3]);
            pf0 = t.v;
            t.u[0] = cvt_pk_bf16(sc[2][0], sc[2][1]);
            t.u[1] = cvt_pk_bf16(sc[2][2], sc[2][3]);
            t.u[2] = cvt_pk_bf16(sc[3][0], sc[3][1]);
            t.u[3] = cvt_pk_bf16(sc[3][2], sc[3][3]);
            pf1 = t.v;
        }

        // ---- O += P V ; L += P 1 (row-sum on the matrix pipe) ----
        const uint* VT0 = &VTs[cur][0][0];
        __builtin_amdgcn_s_setprio(1);
#pragma unroll
        for (int nb = 0; nb < 4; ++nb) {
            const uint* vrow = VT0 + (size_t)(nb * 16 + l16) * 33;
#pragma unroll
            for (int c = 0; c < 2; ++c) {
                const int p0 = (c * 16 + 2 * quad) ^ swd;       // swd bit0 == 0
                const int p2 = (c * 16 + 8 + 2 * quad) ^ swd;
                union { uint u[4]; bf16x8 v; } vf;
                vf.u[0] = vrow[p0];
                vf.u[1] = vrow[p0 + 1];
                vf.u[2] = vrow[p2];
                vf.u[3] = vrow[p2 + 1];
                of[nb] = __builtin_amdgcn_mfma_f32_16x16x32_bf16(
                    c ? pf1 : pf0, vf.v, of[nb], 0, 0, 0);
            }
        }
        of_sum = __builtin_amdgcn_mfma_f32_16x16x32_bf16(pf0, ones, of_sum, 0, 0, 0);
        of_sum = __builtin_amdgcn_mfma_f32_16x16x32_bf16(pf1, ones, of_sum, 0, 0, 0);
        __builtin_amdgcn_s_setprio(0);
    }

    // ---- epilogue: of_sum[r] = L[q = quad*4 + r]; final write always ----
    const int rl0 = quad * 4;
    float linv[4];
#pragma unroll
    for (int r = 0; r < 4; ++r)
        linv[r] = 1.0f / of_sum[r];
#pragma unroll
    for (int nb = 0; nb < 4; ++nb)
#pragma unroll
        for (int r = 0; r < 4; ++r) {
            float v = of[nb][r] * linv[r];
            Attnb[(size_t)(b * SEQ + qrow0 + rl0 + r) * EMB + h * HD + nb * 16 + l16] =
                __float2bfloat16(v);
        }
}

// ---------------------------------------------------------------------------
extern "C" void kernel_launch(void* const* d_in, const int* in_sizes, int n_in,
                              void* d_out, int out_size, void* d_ws, size_t ws_size,
                              hipStream_t stream) {
    const float* x  = (const float*)d_in[0];
    const float* Wq = (const float*)d_in[1];
    const float* Wk = (const float*)d_in[2];
    const float* Wv = (const float*)d_in[3];
    const float* Wo = (const float*)d_in[4];
    float* out = (float*)d_out;

    char* ws = (char*)d_ws;
    size_t off = 0;
    auto alloc = [&](size_t bytes) -> void* {
        void* p = ws + off;
        off += (bytes + 255) & ~(size_t)255;
        return p;
    };

    __hip_bfloat16* xb    = (__hip_bfloat16*)alloc((size_t)NX * 2);
    __hip_bfloat16* Wqkvb = (__hip_bfloat16*)alloc((size_t)NW * 3 * 2);
    __hip_bfloat16* Wob   = (__hip_bfloat16*)alloc((size_t)NW * 2);
    __hip_bfloat16* Qbuf  = (__hip_bfloat16*)alloc((size_t)NX * 2);
    __hip_bfloat16* Kbuf  = (__hip_bfloat16*)alloc((size_t)NX * 2);
    __hip_bfloat16* Vbuf  = (__hip_bfloat16*)alloc((size_t)NX * 2);
    __hip_bfloat16* Attnb = (__hip_bfloat16*)alloc((size_t)NX * 2);
    float2*         ctab  = (float2*)alloc((size_t)SEQ * 32 * sizeof(float2));

    // one-time: allow 128 KB dynamic LDS for the big-tile qkv GEMM
    static bool attrDone = false;
    if (!attrDone) {
        (void)hipFuncSetAttribute((const void*)gemm_qkv_kernel,
                                  hipFuncAttributeMaxDynamicSharedMemorySize,
                                  131072);
        attrDone = true;
    }

    // fused casts + RoPE table (256 tail blocks)
    fused_cast_kernel<<<(NX + 4 * NW) / (256 * 8) + 256, 256, 0, stream>>>(
        x, Wq, Wk, Wv, Wo, xb, Wqkvb, Wob, ctab);

    // fused QKV projection + RoPE epilogue (256x256 big-tile, 1 block/CU)
    dim3 qgrid(3072 / 256, MROWS / 256);    // (12, 16) = 192 blocks
    gemm_qkv_kernel<<<qgrid, 512, 131072, stream>>>(xb, Wqkvb, Qbuf, Kbuf, Vbuf,
                                                    ctab, MROWS, EMB);

    // S^T flash attention: 128-row q-tiles, single owner, balanced pairs
    dim3 agrid(16, 32);
    attn_mfma_kernel<<<agrid, 512, 0, stream>>>(Qbuf, Kbuf, Vbuf, Attnb);

    // output projection -> fp32 d_out (128x64 tiles, 512 blocks)
    dim3 ggrid(EMB / 64, MROWS / 128);
    gemm_oproj_kernel<<<ggrid, 256, 0, stream>>>(Attnb, Wob, out, MROWS, EMB, EMB);
}